// Round 13
// baseline (475.696 us; speedup 1.0000x reference)
//
#include <hip/hip_runtime.h>

// (V, D, H, L, E) = (50000, 128, 128, 4, 160000)
#define V_NODES 50000
#define NEDGE   160000
#define NSEG    (8 * V_NODES)          // 400000 (g,node) segments

typedef __bf16 bf16;
typedef __attribute__((ext_vector_type(8))) __bf16 bf16x8;
typedef __attribute__((ext_vector_type(4))) __bf16 bf16x4;
typedef __attribute__((ext_vector_type(4))) float  f32x4;

__device__ __forceinline__ int clampV(int n) {
  unsigned u = (unsigned)n;
  return (int)(u < (unsigned)V_NODES ? u : (unsigned)(V_NODES - 1));
}

__device__ __forceinline__ float bflo(unsigned u) {
  return __builtin_bit_cast(float, u << 16);
}
__device__ __forceinline__ float bfhi(unsigned u) {
  return __builtin_bit_cast(float, u & 0xffff0000u);
}

// ---------------- standalone prep kernels (fallback path) ------------------

__global__ __launch_bounds__(256) void prep_emb_k(const float* __restrict__ in,
                                                  bf16* __restrict__ out) {
  int i = blockIdx.x * 256 + threadIdx.x;
  float4 v = ((const float4*)in)[i];
  bf16x4 o = {(bf16)v.x, (bf16)v.y, (bf16)v.z, (bf16)v.w};
  *(bf16x4*)(out + (size_t)i * 4) = o;
}

__global__ __launch_bounds__(256) void prep_w1_k(const float* __restrict__ in,
                                                 bf16* __restrict__ out) {
  int idx = blockIdx.x * 256 + threadIdx.x;         // 262144
  int n = idx & 127, k = (idx >> 7) & 255, g = idx >> 15;
  out[(((g << 7) + n) << 8) + k] = (bf16)in[idx];   // w1t[g][n][k]
}

__global__ __launch_bounds__(256) void prep_w2_k(const float* __restrict__ in,
                                                 bf16* __restrict__ out) {
  int idx = blockIdx.x * 256 + threadIdx.x;         // 131072
  int n = idx & 127, k = (idx >> 7) & 127, g = idx >> 14;
  out[(((g << 7) + n) << 7) + k] = (bf16)in[idx];   // w2t[g][n][k]
}

__global__ __launch_bounds__(256) void relu_k(float* __restrict__ out) {
  int i = blockIdx.x * 256 + threadIdx.x;
  float4 v = ((float4*)out)[i];
  v.x = fmaxf(v.x, 0.f); v.y = fmaxf(v.y, 0.f);
  v.z = fmaxf(v.z, 0.f); v.w = fmaxf(v.w, 0.f);
  ((float4*)out)[i] = v;
}

// ---------------- fused prep + dual-ep histogram with RANK capture ---------

__global__ __launch_bounds__(256) void fused_prep_k(
    const float* __restrict__ emb, const float* __restrict__ W1,
    const float* __restrict__ W2,
    const int* __restrict__ a0, const int* __restrict__ a1,
    const int* __restrict__ a2, const int* __restrict__ a3,
    bf16* __restrict__ embB, bf16* __restrict__ w1t, bf16* __restrict__ w2t,
    int* __restrict__ counts, int* __restrict__ rankbuf) {
  const int bx = blockIdx.x, tid = threadIdx.x;
  if (bx < 6250) {
    int i = bx * 256 + tid;
    float4 v = ((const float4*)emb)[i];
    bf16x4 o = {(bf16)v.x, (bf16)v.y, (bf16)v.z, (bf16)v.w};
    *(bf16x4*)(embB + (size_t)i * 4) = o;
  } else if (bx < 7274) {
    int idx = (bx - 6250) * 256 + tid;
    int n = idx & 127, k = (idx >> 7) & 255, g = idx >> 15;
    w1t[(((g << 7) + n) << 8) + k] = (bf16)W1[idx];
  } else if (bx < 7786) {
    int idx = (bx - 7274) * 256 + tid;
    int n = idx & 127, k = (idx >> 7) & 127, g = idx >> 14;
    w2t[(((g << 7) + n) << 7) + k] = (bf16)W2[idx];
  } else {
    int j = bx - 7786;                 // 0..2499
    int l = j / 625;
    int e = (j - l * 625) * 256 + tid; // 0..159999
    const int* adj = (l == 0) ? a0 : (l == 1) ? a1 : (l == 2) ? a2 : a3;
    int2 pr = ((const int2*)adj)[e];
    int src = clampV(pr.x), dst = clampV(pr.y);
    int r0 = atomicAdd(&counts[(2 * l) * V_NODES + src], 1);
    int r1 = atomicAdd(&counts[(2 * l + 1) * V_NODES + dst], 1);
    rankbuf[(2 * l) * NEDGE + e] = r0;       // coalesced
    rankbuf[(2 * l + 1) * NEDGE + e] = r1;   // coalesced
  }
}

// ---------------- CSR scans (plain CSR: offsX[i] = start[i]) ---------------

__global__ __launch_bounds__(256) void scan_a_k(const int* __restrict__ counts,
                                                int* __restrict__ offsX,
                                                int* __restrict__ bsums) {
  __shared__ int sh[256];
  int t = threadIdx.x, base = blockIdx.x * 512;
  int e0 = base + 2 * t, e1 = e0 + 1;
  int a = (e0 < NSEG) ? counts[e0] : 0;
  int b = (e1 < NSEG) ? counts[e1] : 0;
  int s = a + b;
  sh[t] = s;
  __syncthreads();
  #pragma unroll
  for (int d = 1; d < 256; d <<= 1) {
    int v = (t >= d) ? sh[t - d] : 0;
    __syncthreads();
    sh[t] += v;
    __syncthreads();
  }
  int excl = sh[t] - s;
  if (e0 < NSEG) offsX[e0] = excl;
  if (e1 < NSEG) offsX[e1] = excl + a;
  if (t == 255) bsums[blockIdx.x] = sh[255];
}

#define NBLK_SCAN 782   // ceil(400000/512)

// parallel block-sum scan: 4 elems/thread + Hillis-Steele over 256 partials
__global__ __launch_bounds__(256) void scan_b_k(int* __restrict__ bsums,
                                                int* __restrict__ offsX) {
  __shared__ int sh[256];
  int t = threadIdx.x, base = t * 4;
  int v0 = (base + 0 < NBLK_SCAN) ? bsums[base + 0] : 0;
  int v1 = (base + 1 < NBLK_SCAN) ? bsums[base + 1] : 0;
  int v2 = (base + 2 < NBLK_SCAN) ? bsums[base + 2] : 0;
  int v3 = (base + 3 < NBLK_SCAN) ? bsums[base + 3] : 0;
  int s = v0 + v1 + v2 + v3;
  sh[t] = s;
  __syncthreads();
  #pragma unroll
  for (int d = 1; d < 256; d <<= 1) {
    int x = (t >= d) ? sh[t - d] : 0;
    __syncthreads();
    sh[t] += x;
    __syncthreads();
  }
  int run = sh[t] - s;           // exclusive prefix of this thread's chunk
  if (base + 0 < NBLK_SCAN) { bsums[base + 0] = run; run += v0; }
  if (base + 1 < NBLK_SCAN) { bsums[base + 1] = run; run += v1; }
  if (base + 2 < NBLK_SCAN) { bsums[base + 2] = run; run += v2; }
  if (base + 3 < NBLK_SCAN) { bsums[base + 3] = run; run += v3; }
  if (t == 0) offsX[NSEG] = 8 * NEDGE;   // total placements, statically known
}

__global__ __launch_bounds__(256) void scan_c_k(int* __restrict__ offsX,
                                                const int* __restrict__ bsums) {
  int i = blockIdx.x * 256 + threadIdx.x;
  if (i < NSEG) offsX[i] += bsums[i >> 9];
}

// ---------------- atomic-free scatter (rank precomputed in hist) -----------

__global__ __launch_bounds__(256) void scatter2_k(
    const int* __restrict__ a0, const int* __restrict__ a1,
    const int* __restrict__ a2, const int* __restrict__ a3,
    const int* __restrict__ offsX, const int* __restrict__ rankbuf,
    int* __restrict__ ids) {
  int j = blockIdx.x;                // 0..4999
  int g = j / 625;
  int e = (j - g * 625) * 256 + threadIdx.x;
  int l = g >> 1, ep = g & 1;
  const int* adj = (l == 0) ? a0 : (l == 1) ? a1 : (l == 2) ? a2 : a3;
  int2 pr = ((const int2*)adj)[e];
  int src = clampV(pr.x), dst = clampV(pr.y);
  int tgt = ep ? dst : src;
  int oth = ep ? src : dst;
  int pos = offsX[g * V_NODES + tgt] + rankbuf[g * NEDGE + e];
  ids[pos] = oth;
}

// ---------------- Xab xgemm v2: wave-private staging, ZERO barriers --------
// Each wave (h2,dh) computes a complete 16-node x 64-dim half-tile: stage it
// in a wave-private 2KB LDS region (16B-chunk XOR swizzle), wave-scope
// lgkmcnt wait (NO __syncthreads -> global stores pipeline across tiles),
// read back 32B/lane, store coalesced 128B half-rows.

__global__ __launch_bounds__(256) void xab_k(
    const bf16* __restrict__ embB, const bf16* __restrict__ w1t,
    bf16* __restrict__ Xab, int gbase) {
  __shared__ __attribute__((aligned(16))) bf16 stg[4 * 1024];   // 4 waves x 2KB
  const int tid = threadIdx.x;
  const int slot = blockIdx.x / 625, bxx = blockIdx.x - slot * 625;
  const int w = tid >> 6, lane = tid & 63;
  const int l15 = lane & 15, q = lane >> 4;
  const int h2 = w >> 1, dh = w & 1;
  const int g = gbase + slot;

  bf16x8 wA[4][4];
  const bf16* __restrict__ w1g = w1t + (size_t)g * 32768;
  #pragma unroll
  for (int mb = 0; mb < 4; ++mb)
    #pragma unroll
    for (int kb = 0; kb < 4; ++kb)
      wA[mb][kb] = *(const bf16x8*)(w1g + (size_t)(dh * 64 + mb * 16 + l15) * 256 +
                                    h2 * 128 + kb * 32 + q * 8);

  bf16* __restrict__ wstg = stg + w * 1024;      // wave-private 2KB
  const int wnode = lane >> 2, wch = (lane & 3) * 2;   // read-out role
  bf16* __restrict__ Xout = Xab + (size_t)slot * 12800000 + (size_t)h2 * 6400000;

  for (int t = 0; t < 5; ++t) {
    const int nodeB = bxx * 80 + t * 16;
    const int node = nodeB + l15;
    bf16x8 b[4];
    #pragma unroll
    for (int kb = 0; kb < 4; ++kb)
      b[kb] = *(const bf16x8*)(embB + (size_t)node * 128 + kb * 32 + q * 8);

    f32x4 acc[4] = {};
    #pragma unroll
    for (int kb = 0; kb < 4; ++kb)
      #pragma unroll
      for (int mb = 0; mb < 4; ++mb)
        acc[mb] = __builtin_amdgcn_mfma_f32_16x16x32_bf16(wA[mb][kb], b[kb], acc[mb], 0, 0, 0);

    // stage: lane (q,l15) holds dims mb*16+q*4+r of node l15 (within the
    // wave's 64-dim half). 16B chunk c = mb*2 + (q>>1), XOR-swizzled by row.
    #pragma unroll
    for (int mb = 0; mb < 4; ++mb) {
      int c = mb * 2 + (q >> 1);
      int sw = c ^ (l15 & 7);
      bf16x4 o = {(bf16)acc[mb][0], (bf16)acc[mb][1],
                  (bf16)acc[mb][2], (bf16)acc[mb][3]};
      *(bf16x4*)((char*)wstg + l15 * 128 + sw * 16 + (q & 1) * 8) = o;
    }
    asm volatile("s_waitcnt lgkmcnt(0)" ::: "memory");   // wave-scope fence
    uint4 v0 = *(const uint4*)((char*)wstg + wnode * 128 +
                               ((wch ^ (wnode & 7)) << 4));
    uint4 v1 = *(const uint4*)((char*)wstg + wnode * 128 +
                               (((wch + 1) ^ (wnode & 7)) << 4));
    bf16* op = Xout + (size_t)(nodeB + wnode) * 128 + dh * 64 + wch * 8;
    *(uint4*)(op) = v0;
    *(uint4*)(op + 8) = v1;
  }
}

// ---------------- aggregate (r5-proven structure): one segment/HALF-wave ---

__global__ __launch_bounds__(256) void aggf4_k(
    const bf16* __restrict__ Xab,
    const int* __restrict__ offsX, const int* __restrict__ ids,
    bf16* __restrict__ HaggB, int gbase) {
  const int wv = threadIdx.x >> 6, lane = threadIdx.x & 63;
  const int h = lane >> 5, m = lane & 31;
  const int node = blockIdx.x * 8 + wv * 2 + h;
  const int slot = blockIdx.y, g = gbase + slot;
  const int ep = g & 1;
  const bf16* __restrict__ Xa = Xab + (size_t)slot * 12800000;
  const bf16* __restrict__ Xb = Xa + 6400000;
  const bf16* __restrict__ own = ep ? Xb : Xa;   // target side
  const bf16* __restrict__ oth = ep ? Xa : Xb;   // gathered side
  const int seg = g * V_NODES + node;
  const int beg = offsX[seg], end = offsX[seg + 1];

  uint2 uo = *(const uint2*)(own + (size_t)node * 128 + m * 4);
  const float o0 = bflo(uo.x), o1 = bfhi(uo.x);
  const float o2 = bflo(uo.y), o3 = bfhi(uo.y);

  float s0 = 0.f, s1 = 0.f, s2 = 0.f, s3 = 0.f;
  int i = beg;
  for (; i + 2 <= end; i += 2) {
    int n0 = ids[i];
    int n1 = ids[i + 1];
    uint2 u0 = *(const uint2*)(oth + (size_t)n0 * 128 + m * 4);
    uint2 u1 = *(const uint2*)(oth + (size_t)n1 * 128 + m * 4);
    s0 += fmaxf(o0 + bflo(u0.x), 0.f) + fmaxf(o0 + bflo(u1.x), 0.f);
    s1 += fmaxf(o1 + bfhi(u0.x), 0.f) + fmaxf(o1 + bfhi(u1.x), 0.f);
    s2 += fmaxf(o2 + bflo(u0.y), 0.f) + fmaxf(o2 + bflo(u1.y), 0.f);
    s3 += fmaxf(o3 + bfhi(u0.y), 0.f) + fmaxf(o3 + bfhi(u1.y), 0.f);
  }
  if (i < end) {
    int n = ids[i];
    uint2 u = *(const uint2*)(oth + (size_t)n * 128 + m * 4);
    s0 += fmaxf(o0 + bflo(u.x), 0.f);
    s1 += fmaxf(o1 + bfhi(u.x), 0.f);
    s2 += fmaxf(o2 + bflo(u.y), 0.f);
    s3 += fmaxf(o3 + bfhi(u.y), 0.f);
  }
  bf16x4 st = {(bf16)s0, (bf16)s1, (bf16)s2, (bf16)s3};
  *(bf16x4*)(HaggB + ((size_t)g * V_NODES + node) * 128 + m * 4) = st;
}

// ---------------- dense GEMM2 v2: no LDS, no barriers ----------------------
// Block = 32 rows x 128 cols, 4 waves (wave = 32 rows x 32 cols). A frags
// loaded directly from L3-resident Hagg (4x wave redundancy absorbed by
// L2/L3); fully unrolled 8g x 4kb loop -> 96 independent loads + 128 MFMA,
// zero sync points. Over-read rows >= V land in allocated Xab (store-guarded).

__global__ __launch_bounds__(256) void gemm2p_k(const bf16* __restrict__ HaggB,
                                                const bf16* __restrict__ w2t,
                                                float* __restrict__ out) {
  const int tid = threadIdx.x, wv = tid >> 6, lane = tid & 63;
  const int l15 = lane & 15, q = lane >> 4;
  const int v0 = blockIdx.x * 32;

  f32x4 acc[2][2] = {};     // [mt][t]
  #pragma unroll
  for (int g = 0; g < 8; ++g) {
    const bf16* __restrict__ Hg = HaggB + (size_t)g * 6400000;
    const bf16* __restrict__ Wb = w2t + (size_t)g * 16384;
    #pragma unroll
    for (int kb = 0; kb < 4; ++kb) {
      bf16x8 a[2];
      #pragma unroll
      for (int mt = 0; mt < 2; ++mt)
        a[mt] = *(const bf16x8*)(Hg + (size_t)(v0 + mt * 16 + l15) * 128 +
                                 kb * 32 + q * 8);
      #pragma unroll
      for (int t = 0; t < 2; ++t) {
        int n = (wv * 2 + t) * 16 + l15;
        bf16x8 b = *(const bf16x8*)(Wb + (size_t)n * 128 + kb * 32 + q * 8);
        #pragma unroll
        for (int mt = 0; mt < 2; ++mt)
          acc[mt][t] = __builtin_amdgcn_mfma_f32_16x16x32_bf16(a[mt], b, acc[mt][t], 0, 0, 0);
      }
    }
  }

  #pragma unroll
  for (int mt = 0; mt < 2; ++mt)
    #pragma unroll
    for (int r = 0; r < 4; ++r) {
      int row = v0 + mt * 16 + q * 4 + r;
      if (row < V_NODES) {
        #pragma unroll
        for (int t = 0; t < 2; ++t) {
          int col = (wv * 2 + t) * 16 + l15;
          out[(size_t)row * 128 + col] = fmaxf(acc[mt][t][r], 0.f);
        }
      }
    }
}

// ---------------- fallback edge kernel (round-0, proven 637us) -------------

__global__ __launch_bounds__(256) void edge_k(
    const bf16* __restrict__ embB,
    const int* __restrict__ a0, const int* __restrict__ a1,
    const int* __restrict__ a2, const int* __restrict__ a3,
    const bf16* __restrict__ w1t, const bf16* __restrict__ w2t,
    float* __restrict__ out) {

  __shared__ __attribute__((aligned(16))) bf16 w1_lds[128 * 256];
  __shared__ __attribute__((aligned(16))) bf16 h_lds[64 * 128];

  const int tid = threadIdx.x;
  const int g  = blockIdx.x >> 6;
  const int bs = blockIdx.x & 63;
  const int l = g >> 1, ep = g & 1;
  const int* __restrict__ adj = (l == 0) ? a0 : (l == 1) ? a1 : (l == 2) ? a2 : a3;

  {
    const uint4* w1g = (const uint4*)(w1t + (size_t)g * 128 * 256);
    #pragma unroll
    for (int i = 0; i < 16; ++i) {
      int j = i * 256 + tid;
      int n = j >> 5, c = j & 31;
      *(uint4*)(&w1_lds[n * 256 + ((c ^ (n & 7)) << 3)]) = w1g[j];
    }
  }
  __syncthreads();

  const int w    = tid >> 6;
  const int lane = tid & 63;
  const int wr = w >> 1, wc = w & 1;
  const int l15 = lane & 15, q = lane >> 4;
  const bf16* __restrict__ w2g = w2t + (size_t)g * 128 * 128;

  for (int t = bs; t < 2500; t += 64) {
    const int ebase = t * 64;
    int2 pr0 = ((const int2*)adj)[ebase + 32 * wr + l15];
    int2 pr1 = ((const int2*)adj)[ebase + 32 * wr + 16 + l15];
    pr0.x = clampV(pr0.x); pr0.y = clampV(pr0.y);
    pr1.x = clampV(pr1.x); pr1.y = clampV(pr1.y);

    f32x4 acc[2][4] = {};
    #pragma unroll
    for (int kb = 0; kb < 8; ++kb) {
      const int k = kb * 32 + q * 8;
      const int klo = k & 127;
      const int n0 = (kb < 4) ? pr0.x : pr0.y;
      const int n1 = (kb < 4) ? pr1.x : pr1.y;
      bf16x8 a[2], b[4];
      a[0] = *(const bf16x8*)(embB + (size_t)n0 * 128 + klo);
      a[1] = *(const bf16x8*)(embB + (size_t)n1 * 128 + klo);
      const int csw = ((kb << 2) + q);
      #pragma unroll
      for (int nt = 0; nt < 4; ++nt) {
        int n = 64 * wc + 16 * nt + l15;
        b[nt] = *(const bf16x8*)(&w1_lds[n * 256 + ((csw ^ (l15 & 7)) << 3)]);
      }
      #pragma unroll
      for (int mt = 0; mt < 2; ++mt)
        #pragma unroll
        for (int nt = 0; nt < 4; ++nt)
          acc[mt][nt] = __builtin_amdgcn_mfma_f32_16x16x32_bf16(a[mt], b[nt], acc[mt][nt], 0, 0, 0);
    }

    __syncthreads();
    #pragma unroll
    for (int mt = 0; mt < 2; ++mt)
      #pragma unroll
      for (int nt = 0; nt < 4; ++nt)
        #pragma unroll
        for (int r = 0; r < 4; ++r) {
          float v = acc[mt][nt][r];
          v = v > 0.f ? v : 0.f;
          int row = 32 * wr + 16 * mt + 4 * q + r;
          int col = 64 * wc + 16 * nt + l15;
          int c = col >> 3;
          h_lds[row * 128 + (((c ^ (row & 7)) << 3) | (col & 7))] = (bf16)v;
        }
    __syncthreads();

    f32x4 acc2[2][4] = {};
    #pragma unroll
    for (int kb = 0; kb < 4; ++kb) {
      const int k = kb * 32 + q * 8;
      const int csw = (kb << 2) + q;
      bf16x8 a[2], b[4];
      #pragma unroll
      for (int mt = 0; mt < 2; ++mt) {
        int row = 32 * wr + 16 * mt + l15;
        a[mt] = *(const bf16x8*)(&h_lds[row * 128 + ((csw ^ (row & 7)) << 3)]);
      }
      #pragma unroll
      for (int nt = 0; nt < 4; ++nt) {
        int n = 64 * wc + 16 * nt + l15;
        b[nt] = *(const bf16x8*)(w2g + n * 128 + k);
      }
      #pragma unroll
      for (int mt = 0; mt < 2; ++mt)
        #pragma unroll
        for (int nt = 0; nt < 4; ++nt)
          acc2[mt][nt] = __builtin_amdgcn_mfma_f32_16x16x32_bf16(a[mt], b[nt], acc2[mt][nt], 0, 0, 0);
    }

    #pragma unroll
    for (int mt = 0; mt < 2; ++mt)
      #pragma unroll
      for (int r = 0; r < 4; ++r) {
        int row = 32 * wr + 16 * mt + 4 * q + r;
        int2 pr = ((const int2*)adj)[ebase + row];
        int node = clampV(ep ? pr.y : pr.x);
        float* basep = out + (size_t)node * 128 + 64 * wc + l15;
        #pragma unroll
        for (int nt = 0; nt < 4; ++nt)
          unsafeAtomicAdd(basep + 16 * nt, acc2[mt][nt][r]);
      }
  }
}

// ---------------- host launch ----------------------------------------------

extern "C" void kernel_launch(void* const* d_in, const int* in_sizes, int n_in,
                              void* d_out, int out_size, void* d_ws, size_t ws_size,
                              hipStream_t stream) {
  const float* emb = (const float*)d_in[0];
  const int* a0 = (const int*)d_in[1];
  const int* a1 = (const int*)d_in[2];
  const int* a2 = (const int*)d_in[3];
  const int* a3 = (const int*)d_in[4];
  const float* W1 = (const float*)d_in[5];
  const float* W2 = (const float*)d_in[6];
  float* out = (float*)d_out;

  char* ws = (char*)d_ws;
  bf16* embB   = (bf16*)(ws);                    // 12,800,000
  bf16* w1t    = (bf16*)(ws + 12800000);         //    524,288
  bf16* w2t    = (bf16*)(ws + 13324288);         //    262,144
  int*  offsX  = (int*) (ws + 13586432);         //  1,600,016 (400001 ints + pad)
  int*  ids    = (int*) (ws + 15186448);         //  5,120,000 (other-endpoint only)
  int*  bsums  = (int*) (ws + 20306448);         //      3,136
  int*  counts = (int*) (ws + 20309584);         //  1,600,000
  bf16* HaggB  = (bf16*)(ws + 21909584);         // 102,400,000 (all 8 g)
  bf16* Xab    = (bf16*)(ws + 124309584);        // 102,400,000 (4 slots x Xa|Xb)
  const size_t need = 226709584;                 // == proven GG=4 bound (r6)
  // rankbuf (5.12MB) aliases the head of HaggB: written in fused_prep, read
  // in scatter2 — both strictly before aggf4's first write to HaggB.
  int* rankbuf = (int*)HaggB;

  if (ws_size >= need) {
    hipMemsetAsync(counts, 0, 1600000, stream);
    fused_prep_k<<<10286, 256, 0, stream>>>(emb, W1, W2, a0, a1, a2, a3,
                                            embB, w1t, w2t, counts, rankbuf);
    scan_a_k<<<NBLK_SCAN, 256, 0, stream>>>(counts, offsX, bsums);
    scan_b_k<<<1, 256, 0, stream>>>(bsums, offsX);
    scan_c_k<<<1563, 256, 0, stream>>>(offsX, bsums);

    scatter2_k<<<5000, 256, 0, stream>>>(a0, a1, a2, a3, offsX, rankbuf, ids);

    xab_k<<<2500, 256, 0, stream>>>(embB, w1t, Xab, 0);
    aggf4_k<<<dim3(6250, 4), 256, 0, stream>>>(Xab, offsX, ids, HaggB, 0);

    xab_k<<<2500, 256, 0, stream>>>(embB, w1t, Xab, 4);
    aggf4_k<<<dim3(6250, 4), 256, 0, stream>>>(Xab, offsX, ids, HaggB, 4);

    gemm2p_k<<<1563, 256, 0, stream>>>(HaggB, w2t, out);
  } else {
    prep_emb_k<<<6250, 256, 0, stream>>>(emb, embB);
    prep_w1_k<<<1024, 256, 0, stream>>>(W1, w1t);
    prep_w2_k<<<512, 256, 0, stream>>>(W2, w2t);
    hipMemsetAsync(d_out, 0, 25600000, stream);
    edge_k<<<512, 256, 0, stream>>>(embB, a0, a1, a2, a3, w1t, w2t, out);
    relu_k<<<6250, 256, 0, stream>>>(out);
  }
}

// Round 14
// 433.920 us; speedup vs baseline: 1.0963x; 1.0963x over previous
//
#include <hip/hip_runtime.h>

// (V, D, H, L, E) = (50000, 128, 128, 4, 160000)
#define V_NODES 50000
#define NEDGE   160000
#define NSEG    (8 * V_NODES)          // 400000 (g,node) segments

typedef __bf16 bf16;
typedef __attribute__((ext_vector_type(8))) __bf16 bf16x8;
typedef __attribute__((ext_vector_type(4))) __bf16 bf16x4;
typedef __attribute__((ext_vector_type(4))) float  f32x4;

__device__ __forceinline__ int clampV(int n) {
  unsigned u = (unsigned)n;
  return (int)(u < (unsigned)V_NODES ? u : (unsigned)(V_NODES - 1));
}

__device__ __forceinline__ float bflo(unsigned u) {
  return __builtin_bit_cast(float, u << 16);
}
__device__ __forceinline__ float bfhi(unsigned u) {
  return __builtin_bit_cast(float, u & 0xffff0000u);
}

// ---------------- standalone prep kernels (fallback path) ------------------

__global__ __launch_bounds__(256) void prep_emb_k(const float* __restrict__ in,
                                                  bf16* __restrict__ out) {
  int i = blockIdx.x * 256 + threadIdx.x;
  float4 v = ((const float4*)in)[i];
  bf16x4 o = {(bf16)v.x, (bf16)v.y, (bf16)v.z, (bf16)v.w};
  *(bf16x4*)(out + (size_t)i * 4) = o;
}

__global__ __launch_bounds__(256) void prep_w1_k(const float* __restrict__ in,
                                                 bf16* __restrict__ out) {
  int idx = blockIdx.x * 256 + threadIdx.x;         // 262144
  int n = idx & 127, k = (idx >> 7) & 255, g = idx >> 15;
  out[(((g << 7) + n) << 8) + k] = (bf16)in[idx];   // w1t[g][n][k]
}

__global__ __launch_bounds__(256) void prep_w2_k(const float* __restrict__ in,
                                                 bf16* __restrict__ out) {
  int idx = blockIdx.x * 256 + threadIdx.x;         // 131072
  int n = idx & 127, k = (idx >> 7) & 127, g = idx >> 14;
  out[(((g << 7) + n) << 7) + k] = (bf16)in[idx];   // w2t[g][n][k]
}

__global__ __launch_bounds__(256) void relu_k(float* __restrict__ out) {
  int i = blockIdx.x * 256 + threadIdx.x;
  float4 v = ((float4*)out)[i];
  v.x = fmaxf(v.x, 0.f); v.y = fmaxf(v.y, 0.f);
  v.z = fmaxf(v.z, 0.f); v.w = fmaxf(v.w, 0.f);
  ((float4*)out)[i] = v;
}

// ---------------- fused prep + dual-ep histogram with RANK capture ---------

__global__ __launch_bounds__(256) void fused_prep_k(
    const float* __restrict__ emb, const float* __restrict__ W1,
    const float* __restrict__ W2,
    const int* __restrict__ a0, const int* __restrict__ a1,
    const int* __restrict__ a2, const int* __restrict__ a3,
    bf16* __restrict__ embB, bf16* __restrict__ w1t, bf16* __restrict__ w2t,
    int* __restrict__ counts, int* __restrict__ rankbuf) {
  const int bx = blockIdx.x, tid = threadIdx.x;
  if (bx < 6250) {
    int i = bx * 256 + tid;
    float4 v = ((const float4*)emb)[i];
    bf16x4 o = {(bf16)v.x, (bf16)v.y, (bf16)v.z, (bf16)v.w};
    *(bf16x4*)(embB + (size_t)i * 4) = o;
  } else if (bx < 7274) {
    int idx = (bx - 6250) * 256 + tid;
    int n = idx & 127, k = (idx >> 7) & 255, g = idx >> 15;
    w1t[(((g << 7) + n) << 8) + k] = (bf16)W1[idx];
  } else if (bx < 7786) {
    int idx = (bx - 7274) * 256 + tid;
    int n = idx & 127, k = (idx >> 7) & 127, g = idx >> 14;
    w2t[(((g << 7) + n) << 7) + k] = (bf16)W2[idx];
  } else {
    int j = bx - 7786;                 // 0..2499
    int l = j / 625;
    int e = (j - l * 625) * 256 + tid; // 0..159999
    const int* adj = (l == 0) ? a0 : (l == 1) ? a1 : (l == 2) ? a2 : a3;
    int2 pr = ((const int2*)adj)[e];
    int src = clampV(pr.x), dst = clampV(pr.y);
    int r0 = atomicAdd(&counts[(2 * l) * V_NODES + src], 1);
    int r1 = atomicAdd(&counts[(2 * l + 1) * V_NODES + dst], 1);
    rankbuf[(2 * l) * NEDGE + e] = r0;       // coalesced
    rankbuf[(2 * l + 1) * NEDGE + e] = r1;   // coalesced
  }
}

// ---------------- CSR scans (plain CSR: offsX[i] = start[i]) ---------------

__global__ __launch_bounds__(256) void scan_a_k(const int* __restrict__ counts,
                                                int* __restrict__ offsX,
                                                int* __restrict__ bsums) {
  __shared__ int sh[256];
  int t = threadIdx.x, base = blockIdx.x * 512;
  int e0 = base + 2 * t, e1 = e0 + 1;
  int a = (e0 < NSEG) ? counts[e0] : 0;
  int b = (e1 < NSEG) ? counts[e1] : 0;
  int s = a + b;
  sh[t] = s;
  __syncthreads();
  #pragma unroll
  for (int d = 1; d < 256; d <<= 1) {
    int v = (t >= d) ? sh[t - d] : 0;
    __syncthreads();
    sh[t] += v;
    __syncthreads();
  }
  int excl = sh[t] - s;
  if (e0 < NSEG) offsX[e0] = excl;
  if (e1 < NSEG) offsX[e1] = excl + a;
  if (t == 255) bsums[blockIdx.x] = sh[255];
}

#define NBLK_SCAN 782   // ceil(400000/512)

// parallel block-sum scan: 4 elems/thread + Hillis-Steele over 256 partials
__global__ __launch_bounds__(256) void scan_b_k(int* __restrict__ bsums,
                                                int* __restrict__ offsX) {
  __shared__ int sh[256];
  int t = threadIdx.x, base = t * 4;
  int v0 = (base + 0 < NBLK_SCAN) ? bsums[base + 0] : 0;
  int v1 = (base + 1 < NBLK_SCAN) ? bsums[base + 1] : 0;
  int v2 = (base + 2 < NBLK_SCAN) ? bsums[base + 2] : 0;
  int v3 = (base + 3 < NBLK_SCAN) ? bsums[base + 3] : 0;
  int s = v0 + v1 + v2 + v3;
  sh[t] = s;
  __syncthreads();
  #pragma unroll
  for (int d = 1; d < 256; d <<= 1) {
    int x = (t >= d) ? sh[t - d] : 0;
    __syncthreads();
    sh[t] += x;
    __syncthreads();
  }
  int run = sh[t] - s;           // exclusive prefix of this thread's chunk
  if (base + 0 < NBLK_SCAN) { bsums[base + 0] = run; run += v0; }
  if (base + 1 < NBLK_SCAN) { bsums[base + 1] = run; run += v1; }
  if (base + 2 < NBLK_SCAN) { bsums[base + 2] = run; run += v2; }
  if (base + 3 < NBLK_SCAN) { bsums[base + 3] = run; run += v3; }
  if (t == 0) offsX[NSEG] = 8 * NEDGE;   // total placements, statically known
}

__global__ __launch_bounds__(256) void scan_c_k(int* __restrict__ offsX,
                                                const int* __restrict__ bsums) {
  int i = blockIdx.x * 256 + threadIdx.x;
  if (i < NSEG) offsX[i] += bsums[i >> 9];
}

// ---------------- atomic-free scatter (rank precomputed in hist) -----------

__global__ __launch_bounds__(256) void scatter2_k(
    const int* __restrict__ a0, const int* __restrict__ a1,
    const int* __restrict__ a2, const int* __restrict__ a3,
    const int* __restrict__ offsX, const int* __restrict__ rankbuf,
    int* __restrict__ ids) {
  int j = blockIdx.x;                // 0..4999
  int g = j / 625;
  int e = (j - g * 625) * 256 + threadIdx.x;
  int l = g >> 1, ep = g & 1;
  const int* adj = (l == 0) ? a0 : (l == 1) ? a1 : (l == 2) ? a2 : a3;
  int2 pr = ((const int2*)adj)[e];
  int src = clampV(pr.x), dst = clampV(pr.y);
  int tgt = ep ? dst : src;
  int oth = ep ? src : dst;
  int pos = offsX[g * V_NODES + tgt] + rankbuf[g * NEDGE + e];
  ids[pos] = oth;
}

// ---------------- Xab xgemm v2: wave-private staging, ZERO barriers --------
// (kept from r13: saved ~12us vs barrier version)

__global__ __launch_bounds__(256) void xab_k(
    const bf16* __restrict__ embB, const bf16* __restrict__ w1t,
    bf16* __restrict__ Xab, int gbase) {
  __shared__ __attribute__((aligned(16))) bf16 stg[4 * 1024];   // 4 waves x 2KB
  const int tid = threadIdx.x;
  const int slot = blockIdx.x / 625, bxx = blockIdx.x - slot * 625;
  const int w = tid >> 6, lane = tid & 63;
  const int l15 = lane & 15, q = lane >> 4;
  const int h2 = w >> 1, dh = w & 1;
  const int g = gbase + slot;

  bf16x8 wA[4][4];
  const bf16* __restrict__ w1g = w1t + (size_t)g * 32768;
  #pragma unroll
  for (int mb = 0; mb < 4; ++mb)
    #pragma unroll
    for (int kb = 0; kb < 4; ++kb)
      wA[mb][kb] = *(const bf16x8*)(w1g + (size_t)(dh * 64 + mb * 16 + l15) * 256 +
                                    h2 * 128 + kb * 32 + q * 8);

  bf16* __restrict__ wstg = stg + w * 1024;      // wave-private 2KB
  const int wnode = lane >> 2, wch = (lane & 3) * 2;   // read-out role
  bf16* __restrict__ Xout = Xab + (size_t)slot * 12800000 + (size_t)h2 * 6400000;

  for (int t = 0; t < 5; ++t) {
    const int nodeB = bxx * 80 + t * 16;
    const int node = nodeB + l15;
    bf16x8 b[4];
    #pragma unroll
    for (int kb = 0; kb < 4; ++kb)
      b[kb] = *(const bf16x8*)(embB + (size_t)node * 128 + kb * 32 + q * 8);

    f32x4 acc[4] = {};
    #pragma unroll
    for (int kb = 0; kb < 4; ++kb)
      #pragma unroll
      for (int mb = 0; mb < 4; ++mb)
        acc[mb] = __builtin_amdgcn_mfma_f32_16x16x32_bf16(wA[mb][kb], b[kb], acc[mb], 0, 0, 0);

    #pragma unroll
    for (int mb = 0; mb < 4; ++mb) {
      int c = mb * 2 + (q >> 1);
      int sw = c ^ (l15 & 7);
      bf16x4 o = {(bf16)acc[mb][0], (bf16)acc[mb][1],
                  (bf16)acc[mb][2], (bf16)acc[mb][3]};
      *(bf16x4*)((char*)wstg + l15 * 128 + sw * 16 + (q & 1) * 8) = o;
    }
    asm volatile("s_waitcnt lgkmcnt(0)" ::: "memory");   // wave-scope fence
    uint4 v0 = *(const uint4*)((char*)wstg + wnode * 128 +
                               ((wch ^ (wnode & 7)) << 4));
    uint4 v1 = *(const uint4*)((char*)wstg + wnode * 128 +
                               (((wch + 1) ^ (wnode & 7)) << 4));
    bf16* op = Xout + (size_t)(nodeB + wnode) * 128 + dh * 64 + wch * 8;
    *(uint4*)(op) = v0;
    *(uint4*)(op + 8) = v1;
  }
}

// ---------------- aggregate (r5-proven structure): one segment/HALF-wave ---

__global__ __launch_bounds__(256) void aggf4_k(
    const bf16* __restrict__ Xab,
    const int* __restrict__ offsX, const int* __restrict__ ids,
    bf16* __restrict__ HaggB, int gbase) {
  const int wv = threadIdx.x >> 6, lane = threadIdx.x & 63;
  const int h = lane >> 5, m = lane & 31;
  const int node = blockIdx.x * 8 + wv * 2 + h;
  const int slot = blockIdx.y, g = gbase + slot;
  const int ep = g & 1;
  const bf16* __restrict__ Xa = Xab + (size_t)slot * 12800000;
  const bf16* __restrict__ Xb = Xa + 6400000;
  const bf16* __restrict__ own = ep ? Xb : Xa;   // target side
  const bf16* __restrict__ oth = ep ? Xa : Xb;   // gathered side
  const int seg = g * V_NODES + node;
  const int beg = offsX[seg], end = offsX[seg + 1];

  uint2 uo = *(const uint2*)(own + (size_t)node * 128 + m * 4);
  const float o0 = bflo(uo.x), o1 = bfhi(uo.x);
  const float o2 = bflo(uo.y), o3 = bfhi(uo.y);

  float s0 = 0.f, s1 = 0.f, s2 = 0.f, s3 = 0.f;
  int i = beg;
  for (; i + 2 <= end; i += 2) {
    int n0 = ids[i];
    int n1 = ids[i + 1];
    uint2 u0 = *(const uint2*)(oth + (size_t)n0 * 128 + m * 4);
    uint2 u1 = *(const uint2*)(oth + (size_t)n1 * 128 + m * 4);
    s0 += fmaxf(o0 + bflo(u0.x), 0.f) + fmaxf(o0 + bflo(u1.x), 0.f);
    s1 += fmaxf(o1 + bfhi(u0.x), 0.f) + fmaxf(o1 + bfhi(u1.x), 0.f);
    s2 += fmaxf(o2 + bflo(u0.y), 0.f) + fmaxf(o2 + bflo(u1.y), 0.f);
    s3 += fmaxf(o3 + bfhi(u0.y), 0.f) + fmaxf(o3 + bfhi(u1.y), 0.f);
  }
  if (i < end) {
    int n = ids[i];
    uint2 u = *(const uint2*)(oth + (size_t)n * 128 + m * 4);
    s0 += fmaxf(o0 + bflo(u.x), 0.f);
    s1 += fmaxf(o1 + bfhi(u.x), 0.f);
    s2 += fmaxf(o2 + bflo(u.y), 0.f);
    s3 += fmaxf(o3 + bfhi(u.y), 0.f);
  }
  bf16x4 st = {(bf16)s0, (bf16)s1, (bf16)s2, (bf16)s3};
  *(bf16x4*)(HaggB + ((size_t)g * V_NODES + node) * 128 + m * 4) = st;
}

// ---------------- dense GEMM2 (LDS-staged A; r12-proven ~55us) -------------

__global__ __launch_bounds__(256) void gemm2p_k(const bf16* __restrict__ HaggB,
                                                const bf16* __restrict__ w2t,
                                                float* __restrict__ out) {
  __shared__ __attribute__((aligned(16))) bf16 a_lds[32 * 128];   // 8KB

  const int tid = threadIdx.x, wv = tid >> 6, lane = tid & 63;
  const int l15 = lane & 15, q = lane >> 4;
  const int v0 = blockIdx.x * 32;

  const int srow = tid >> 3, sc0 = (tid & 7) * 2;
  bf16* sp0 = &a_lds[srow * 128 + ((sc0 ^ (srow & 7)) << 3)];
  bf16* sp1 = &a_lds[srow * 128 + (((sc0 + 1) ^ (srow & 7)) << 3)];

  const uint4* Hg = (const uint4*)(HaggB + (size_t)v0 * 128);
  uint4 s0 = Hg[tid * 2], s1 = Hg[tid * 2 + 1];

  f32x4 acc[2][2] = {};     // [mt][t]
  for (int g = 0; g < 8; ++g) {
    __syncthreads();
    *(uint4*)sp0 = s0;
    *(uint4*)sp1 = s1;
    if (g < 7) {
      const uint4* Hn = (const uint4*)(HaggB + (size_t)(g + 1) * 6400000 +
                                       (size_t)v0 * 128);
      s0 = Hn[tid * 2];
      s1 = Hn[tid * 2 + 1];
    }
    __syncthreads();

    const bf16* __restrict__ Wb = w2t + (size_t)g * 16384;
    #pragma unroll
    for (int kb = 0; kb < 4; ++kb) {
      bf16x8 a[2];
      #pragma unroll
      for (int mt = 0; mt < 2; ++mt) {
        int r = mt * 16 + l15;
        a[mt] = *(const bf16x8*)(&a_lds[r * 128 + (((kb * 4 + q) ^ (r & 7)) << 3)]);
      }
      #pragma unroll
      for (int t = 0; t < 2; ++t) {
        int n = (wv * 2 + t) * 16 + l15;
        bf16x8 b = *(const bf16x8*)(Wb + (size_t)n * 128 + kb * 32 + q * 8);
        #pragma unroll
        for (int mt = 0; mt < 2; ++mt)
          acc[mt][t] = __builtin_amdgcn_mfma_f32_16x16x32_bf16(a[mt], b, acc[mt][t], 0, 0, 0);
      }
    }
  }

  #pragma unroll
  for (int mt = 0; mt < 2; ++mt)
    #pragma unroll
    for (int r = 0; r < 4; ++r) {
      int row = v0 + mt * 16 + q * 4 + r;
      if (row < V_NODES) {
        #pragma unroll
        for (int t = 0; t < 2; ++t) {
          int col = (wv * 2 + t) * 16 + l15;
          out[(size_t)row * 128 + col] = fmaxf(acc[mt][t][r], 0.f);
        }
      }
    }
}

// ---------------- fallback edge kernel (round-0, proven 637us) -------------

__global__ __launch_bounds__(256) void edge_k(
    const bf16* __restrict__ embB,
    const int* __restrict__ a0, const int* __restrict__ a1,
    const int* __restrict__ a2, const int* __restrict__ a3,
    const bf16* __restrict__ w1t, const bf16* __restrict__ w2t,
    float* __restrict__ out) {

  __shared__ __attribute__((aligned(16))) bf16 w1_lds[128 * 256];
  __shared__ __attribute__((aligned(16))) bf16 h_lds[64 * 128];

  const int tid = threadIdx.x;
  const int g  = blockIdx.x >> 6;
  const int bs = blockIdx.x & 63;
  const int l = g >> 1, ep = g & 1;
  const int* __restrict__ adj = (l == 0) ? a0 : (l == 1) ? a1 : (l == 2) ? a2 : a3;

  {
    const uint4* w1g = (const uint4*)(w1t + (size_t)g * 128 * 256);
    #pragma unroll
    for (int i = 0; i < 16; ++i) {
      int j = i * 256 + tid;
      int n = j >> 5, c = j & 31;
      *(uint4*)(&w1_lds[n * 256 + ((c ^ (n & 7)) << 3)]) = w1g[j];
    }
  }
  __syncthreads();

  const int w    = tid >> 6;
  const int lane = tid & 63;
  const int wr = w >> 1, wc = w & 1;
  const int l15 = lane & 15, q = lane >> 4;
  const bf16* __restrict__ w2g = w2t + (size_t)g * 128 * 128;

  for (int t = bs; t < 2500; t += 64) {
    const int ebase = t * 64;
    int2 pr0 = ((const int2*)adj)[ebase + 32 * wr + l15];
    int2 pr1 = ((const int2*)adj)[ebase + 32 * wr + 16 + l15];
    pr0.x = clampV(pr0.x); pr0.y = clampV(pr0.y);
    pr1.x = clampV(pr1.x); pr1.y = clampV(pr1.y);

    f32x4 acc[2][4] = {};
    #pragma unroll
    for (int kb = 0; kb < 8; ++kb) {
      const int k = kb * 32 + q * 8;
      const int klo = k & 127;
      const int n0 = (kb < 4) ? pr0.x : pr0.y;
      const int n1 = (kb < 4) ? pr1.x : pr1.y;
      bf16x8 a[2], b[4];
      a[0] = *(const bf16x8*)(embB + (size_t)n0 * 128 + klo);
      a[1] = *(const bf16x8*)(embB + (size_t)n1 * 128 + klo);
      const int csw = ((kb << 2) + q);
      #pragma unroll
      for (int nt = 0; nt < 4; ++nt) {
        int n = 64 * wc + 16 * nt + l15;
        b[nt] = *(const bf16x8*)(&w1_lds[n * 256 + ((csw ^ (l15 & 7)) << 3)]);
      }
      #pragma unroll
      for (int mt = 0; mt < 2; ++mt)
        #pragma unroll
        for (int nt = 0; nt < 4; ++nt)
          acc[mt][nt] = __builtin_amdgcn_mfma_f32_16x16x32_bf16(a[mt], b[nt], acc[mt][nt], 0, 0, 0);
    }

    __syncthreads();
    #pragma unroll
    for (int mt = 0; mt < 2; ++mt)
      #pragma unroll
      for (int nt = 0; nt < 4; ++nt)
        #pragma unroll
        for (int r = 0; r < 4; ++r) {
          float v = acc[mt][nt][r];
          v = v > 0.f ? v : 0.f;
          int row = 32 * wr + 16 * mt + 4 * q + r;
          int col = 64 * wc + 16 * nt + l15;
          int c = col >> 3;
          h_lds[row * 128 + (((c ^ (row & 7)) << 3) | (col & 7))] = (bf16)v;
        }
    __syncthreads();

    f32x4 acc2[2][4] = {};
    #pragma unroll
    for (int kb = 0; kb < 4; ++kb) {
      const int k = kb * 32 + q * 8;
      const int csw = (kb << 2) + q;
      bf16x8 a[2], b[4];
      #pragma unroll
      for (int mt = 0; mt < 2; ++mt) {
        int row = 32 * wr + 16 * mt + l15;
        a[mt] = *(const bf16x8*)(&h_lds[row * 128 + ((csw ^ (row & 7)) << 3)]);
      }
      #pragma unroll
      for (int nt = 0; nt < 4; ++nt) {
        int n = 64 * wc + 16 * nt + l15;
        b[nt] = *(const bf16x8*)(w2g + n * 128 + k);
      }
      #pragma unroll
      for (int mt = 0; mt < 2; ++mt)
        #pragma unroll
        for (int nt = 0; nt < 4; ++nt)
          acc2[mt][nt] = __builtin_amdgcn_mfma_f32_16x16x32_bf16(a[mt], b[nt], acc2[mt][nt], 0, 0, 0);
    }

    #pragma unroll
    for (int mt = 0; mt < 2; ++mt)
      #pragma unroll
      for (int r = 0; r < 4; ++r) {
        int row = 32 * wr + 16 * mt + 4 * q + r;
        int2 pr = ((const int2*)adj)[ebase + row];
        int node = clampV(ep ? pr.y : pr.x);
        float* basep = out + (size_t)node * 128 + 64 * wc + l15;
        #pragma unroll
        for (int nt = 0; nt < 4; ++nt)
          unsafeAtomicAdd(basep + 16 * nt, acc2[mt][nt][r]);
      }
  }
}

// ---------------- host launch ----------------------------------------------

extern "C" void kernel_launch(void* const* d_in, const int* in_sizes, int n_in,
                              void* d_out, int out_size, void* d_ws, size_t ws_size,
                              hipStream_t stream) {
  const float* emb = (const float*)d_in[0];
  const int* a0 = (const int*)d_in[1];
  const int* a1 = (const int*)d_in[2];
  const int* a2 = (const int*)d_in[3];
  const int* a3 = (const int*)d_in[4];
  const float* W1 = (const float*)d_in[5];
  const float* W2 = (const float*)d_in[6];
  float* out = (float*)d_out;

  char* ws = (char*)d_ws;
  bf16* embB   = (bf16*)(ws);                    // 12,800,000
  bf16* w1t    = (bf16*)(ws + 12800000);         //    524,288
  bf16* w2t    = (bf16*)(ws + 13324288);         //    262,144
  int*  offsX  = (int*) (ws + 13586432);         //  1,600,016 (400001 ints + pad)
  int*  ids    = (int*) (ws + 15186448);         //  5,120,000 (other-endpoint only)
  int*  bsums  = (int*) (ws + 20306448);         //      3,136
  int*  counts = (int*) (ws + 20309584);         //  1,600,000
  bf16* HaggB  = (bf16*)(ws + 21909584);         // 102,400,000 (all 8 g)
  bf16* Xab    = (bf16*)(ws + 124309584);        // 102,400,000 (4 slots x Xa|Xb)
  const size_t need = 226709584;                 // == proven GG=4 bound (r6)
  // rankbuf (5.12MB) aliases the head of HaggB: written in fused_prep, read
  // in scatter2 — both strictly before aggf4's first write to HaggB.
  int* rankbuf = (int*)HaggB;

  if (ws_size >= need) {
    hipMemsetAsync(counts, 0, 1600000, stream);
    fused_prep_k<<<10286, 256, 0, stream>>>(emb, W1, W2, a0, a1, a2, a3,
                                            embB, w1t, w2t, counts, rankbuf);
    scan_a_k<<<NBLK_SCAN, 256, 0, stream>>>(counts, offsX, bsums);
    scan_b_k<<<1, 256, 0, stream>>>(bsums, offsX);
    scan_c_k<<<1563, 256, 0, stream>>>(offsX, bsums);

    scatter2_k<<<5000, 256, 0, stream>>>(a0, a1, a2, a3, offsX, rankbuf, ids);

    xab_k<<<2500, 256, 0, stream>>>(embB, w1t, Xab, 0);
    aggf4_k<<<dim3(6250, 4), 256, 0, stream>>>(Xab, offsX, ids, HaggB, 0);

    xab_k<<<2500, 256, 0, stream>>>(embB, w1t, Xab, 4);
    aggf4_k<<<dim3(6250, 4), 256, 0, stream>>>(Xab, offsX, ids, HaggB, 4);

    gemm2p_k<<<1563, 256, 0, stream>>>(HaggB, w2t, out);
  } else {
    prep_emb_k<<<6250, 256, 0, stream>>>(emb, embB);
    prep_w1_k<<<1024, 256, 0, stream>>>(W1, w1t);
    prep_w2_k<<<512, 256, 0, stream>>>(W2, w2t);
    hipMemsetAsync(d_out, 0, 25600000, stream);
    edge_k<<<512, 256, 0, stream>>>(embB, a0, a1, a2, a3, w1t, w2t, out);
    relu_k<<<6250, 256, 0, stream>>>(out);
  }
}

// Round 15
// 430.871 us; speedup vs baseline: 1.1040x; 1.0071x over previous
//
#include <hip/hip_runtime.h>

// (V, D, H, L, E) = (50000, 128, 128, 4, 160000)
#define V_NODES 50000
#define NEDGE   160000
#define NSEG    (8 * V_NODES)          // 400000 (g,node) segments

typedef __bf16 bf16;
typedef __attribute__((ext_vector_type(8))) __bf16 bf16x8;
typedef __attribute__((ext_vector_type(4))) __bf16 bf16x4;
typedef __attribute__((ext_vector_type(4))) float  f32x4;

__device__ __forceinline__ int clampV(int n) {
  unsigned u = (unsigned)n;
  return (int)(u < (unsigned)V_NODES ? u : (unsigned)(V_NODES - 1));
}

__device__ __forceinline__ float bflo(unsigned u) {
  return __builtin_bit_cast(float, u << 16);
}
__device__ __forceinline__ float bfhi(unsigned u) {
  return __builtin_bit_cast(float, u & 0xffff0000u);
}

// ---------------- standalone prep kernels (fallback path) ------------------

__global__ __launch_bounds__(256) void prep_emb_k(const float* __restrict__ in,
                                                  bf16* __restrict__ out) {
  int i = blockIdx.x * 256 + threadIdx.x;
  float4 v = ((const float4*)in)[i];
  bf16x4 o = {(bf16)v.x, (bf16)v.y, (bf16)v.z, (bf16)v.w};
  *(bf16x4*)(out + (size_t)i * 4) = o;
}

__global__ __launch_bounds__(256) void prep_w1_k(const float* __restrict__ in,
                                                 bf16* __restrict__ out) {
  int idx = blockIdx.x * 256 + threadIdx.x;         // 262144
  int n = idx & 127, k = (idx >> 7) & 255, g = idx >> 15;
  out[(((g << 7) + n) << 8) + k] = (bf16)in[idx];   // w1t[g][n][k]
}

__global__ __launch_bounds__(256) void prep_w2_k(const float* __restrict__ in,
                                                 bf16* __restrict__ out) {
  int idx = blockIdx.x * 256 + threadIdx.x;         // 131072
  int n = idx & 127, k = (idx >> 7) & 127, g = idx >> 14;
  out[(((g << 7) + n) << 7) + k] = (bf16)in[idx];   // w2t[g][n][k]
}

__global__ __launch_bounds__(256) void relu_k(float* __restrict__ out) {
  int i = blockIdx.x * 256 + threadIdx.x;
  float4 v = ((float4*)out)[i];
  v.x = fmaxf(v.x, 0.f); v.y = fmaxf(v.y, 0.f);
  v.z = fmaxf(v.z, 0.f); v.w = fmaxf(v.w, 0.f);
  ((float4*)out)[i] = v;
}

// ---------------- fused prep + INTERLEAVED dual-ep hist (rank capture) -----
// Roles interleaved so hist blocks (atomic-latency-bound) co-reside with
// streaming blocks (HBM-BW-bound): bx<10000 && bx%4==3 -> hist j=bx>>2;
// other bx -> streaming s (emb [0,6250), W1 [6250,7274), W2 [7274,7786)).
// Hist's atomicAdd RETURN VALUE = edge's rank within its segment, stored
// coalesced so the scatter needs no atomics.

__global__ __launch_bounds__(256) void fused_prep_k(
    const float* __restrict__ emb, const float* __restrict__ W1,
    const float* __restrict__ W2,
    const int* __restrict__ a0, const int* __restrict__ a1,
    const int* __restrict__ a2, const int* __restrict__ a3,
    bf16* __restrict__ embB, bf16* __restrict__ w1t, bf16* __restrict__ w2t,
    int* __restrict__ counts, int* __restrict__ rankbuf) {
  const int bx = blockIdx.x, tid = threadIdx.x;
  if (bx < 10000 && (bx & 3) == 3) {
    int j = bx >> 2;                   // 0..2499
    int l = j / 625;
    int e = (j - l * 625) * 256 + tid; // 0..159999
    const int* adj = (l == 0) ? a0 : (l == 1) ? a1 : (l == 2) ? a2 : a3;
    int2 pr = ((const int2*)adj)[e];
    int src = clampV(pr.x), dst = clampV(pr.y);
    int r0 = atomicAdd(&counts[(2 * l) * V_NODES + src], 1);
    int r1 = atomicAdd(&counts[(2 * l + 1) * V_NODES + dst], 1);
    rankbuf[(2 * l) * NEDGE + e] = r0;       // coalesced
    rankbuf[(2 * l + 1) * NEDGE + e] = r1;   // coalesced
  } else {
    int s = (bx < 10000) ? (bx - ((bx + 1) >> 2)) : (7500 + bx - 10000);
    if (s < 6250) {
      int i = s * 256 + tid;
      float4 v = ((const float4*)emb)[i];
      bf16x4 o = {(bf16)v.x, (bf16)v.y, (bf16)v.z, (bf16)v.w};
      *(bf16x4*)(embB + (size_t)i * 4) = o;
    } else if (s < 7274) {
      int idx = (s - 6250) * 256 + tid;
      int n = idx & 127, k = (idx >> 7) & 255, g = idx >> 15;
      w1t[(((g << 7) + n) << 8) + k] = (bf16)W1[idx];
    } else {
      int idx = (s - 7274) * 256 + tid;
      int n = idx & 127, k = (idx >> 7) & 127, g = idx >> 14;
      w2t[(((g << 7) + n) << 7) + k] = (bf16)W2[idx];
    }
  }
}

// ---------------- CSR scans ------------------------------------------------
// offsP[i] = WITHIN-512-BLOCK exclusive prefix (scan_a); bsums = exclusive
// block prefix (scan_b). Consumers compute offs(i) = offsP[i]+bsums[i>>9]
// on the fly (scan_c folded away). offsP[NSEG] set so offs(NSEG)=8*NEDGE.

__global__ __launch_bounds__(256) void scan_a_k(const int* __restrict__ counts,
                                                int* __restrict__ offsP,
                                                int* __restrict__ bsums) {
  __shared__ int sh[256];
  int t = threadIdx.x, base = blockIdx.x * 512;
  int e0 = base + 2 * t, e1 = e0 + 1;
  int a = (e0 < NSEG) ? counts[e0] : 0;
  int b = (e1 < NSEG) ? counts[e1] : 0;
  int s = a + b;
  sh[t] = s;
  __syncthreads();
  #pragma unroll
  for (int d = 1; d < 256; d <<= 1) {
    int v = (t >= d) ? sh[t - d] : 0;
    __syncthreads();
    sh[t] += v;
    __syncthreads();
  }
  int excl = sh[t] - s;
  if (e0 < NSEG) offsP[e0] = excl;
  if (e1 < NSEG) offsP[e1] = excl + a;
  if (t == 255) bsums[blockIdx.x] = sh[255];
}

#define NBLK_SCAN 782   // ceil(400000/512)

// parallel block-sum scan: 4 elems/thread + Hillis-Steele over 256 partials.
// Also writes offsP[NSEG] = 8*NEDGE - bsums_final[NBLK_SCAN-1] so that
// offs(NSEG) = offsP[NSEG] + bsums[NSEG>>9=781] = 8*NEDGE.
__global__ __launch_bounds__(256) void scan_b_k(int* __restrict__ bsums,
                                                int* __restrict__ offsP) {
  __shared__ int sh[256];
  int t = threadIdx.x, base = t * 4;
  int v0 = (base + 0 < NBLK_SCAN) ? bsums[base + 0] : 0;
  int v1 = (base + 1 < NBLK_SCAN) ? bsums[base + 1] : 0;
  int v2 = (base + 2 < NBLK_SCAN) ? bsums[base + 2] : 0;
  int v3 = (base + 3 < NBLK_SCAN) ? bsums[base + 3] : 0;
  int s = v0 + v1 + v2 + v3;
  sh[t] = s;
  __syncthreads();
  #pragma unroll
  for (int d = 1; d < 256; d <<= 1) {
    int x = (t >= d) ? sh[t - d] : 0;
    __syncthreads();
    sh[t] += x;
    __syncthreads();
  }
  int run = sh[t] - s;           // exclusive prefix of this thread's chunk
  if (base + 0 < NBLK_SCAN) {
    bsums[base + 0] = run;
    if (base + 0 == NBLK_SCAN - 1) offsP[NSEG] = 8 * NEDGE - run;
    run += v0;
  }
  if (base + 1 < NBLK_SCAN) {
    bsums[base + 1] = run;
    if (base + 1 == NBLK_SCAN - 1) offsP[NSEG] = 8 * NEDGE - run;
    run += v1;
  }
  if (base + 2 < NBLK_SCAN) {
    bsums[base + 2] = run;
    if (base + 2 == NBLK_SCAN - 1) offsP[NSEG] = 8 * NEDGE - run;
    run += v2;
  }
  if (base + 3 < NBLK_SCAN) {
    bsums[base + 3] = run;
    if (base + 3 == NBLK_SCAN - 1) offsP[NSEG] = 8 * NEDGE - run;
    run += v3;
  }
}

// ---------------- atomic-free scatter (rank precomputed in hist) -----------

__global__ __launch_bounds__(256) void scatter2_k(
    const int* __restrict__ a0, const int* __restrict__ a1,
    const int* __restrict__ a2, const int* __restrict__ a3,
    const int* __restrict__ offsP, const int* __restrict__ bsums,
    const int* __restrict__ rankbuf, int* __restrict__ ids) {
  int j = blockIdx.x;                // 0..4999
  int g = j / 625;
  int e = (j - g * 625) * 256 + threadIdx.x;
  int l = g >> 1, ep = g & 1;
  const int* adj = (l == 0) ? a0 : (l == 1) ? a1 : (l == 2) ? a2 : a3;
  int2 pr = ((const int2*)adj)[e];
  int src = clampV(pr.x), dst = clampV(pr.y);
  int tgt = ep ? dst : src;
  int oth = ep ? src : dst;
  int seg = g * V_NODES + tgt;
  int pos = offsP[seg] + bsums[seg >> 9] + rankbuf[g * NEDGE + e];
  ids[pos] = oth;
}

// ---------------- Xab xgemm v2: wave-private staging, ZERO barriers --------

__global__ __launch_bounds__(256) void xab_k(
    const bf16* __restrict__ embB, const bf16* __restrict__ w1t,
    bf16* __restrict__ Xab, int gbase) {
  __shared__ __attribute__((aligned(16))) bf16 stg[4 * 1024];   // 4 waves x 2KB
  const int tid = threadIdx.x;
  const int slot = blockIdx.x / 625, bxx = blockIdx.x - slot * 625;
  const int w = tid >> 6, lane = tid & 63;
  const int l15 = lane & 15, q = lane >> 4;
  const int h2 = w >> 1, dh = w & 1;
  const int g = gbase + slot;

  bf16x8 wA[4][4];
  const bf16* __restrict__ w1g = w1t + (size_t)g * 32768;
  #pragma unroll
  for (int mb = 0; mb < 4; ++mb)
    #pragma unroll
    for (int kb = 0; kb < 4; ++kb)
      wA[mb][kb] = *(const bf16x8*)(w1g + (size_t)(dh * 64 + mb * 16 + l15) * 256 +
                                    h2 * 128 + kb * 32 + q * 8);

  bf16* __restrict__ wstg = stg + w * 1024;      // wave-private 2KB
  const int wnode = lane >> 2, wch = (lane & 3) * 2;   // read-out role
  bf16* __restrict__ Xout = Xab + (size_t)slot * 12800000 + (size_t)h2 * 6400000;

  for (int t = 0; t < 5; ++t) {
    const int nodeB = bxx * 80 + t * 16;
    const int node = nodeB + l15;
    bf16x8 b[4];
    #pragma unroll
    for (int kb = 0; kb < 4; ++kb)
      b[kb] = *(const bf16x8*)(embB + (size_t)node * 128 + kb * 32 + q * 8);

    f32x4 acc[4] = {};
    #pragma unroll
    for (int kb = 0; kb < 4; ++kb)
      #pragma unroll
      for (int mb = 0; mb < 4; ++mb)
        acc[mb] = __builtin_amdgcn_mfma_f32_16x16x32_bf16(wA[mb][kb], b[kb], acc[mb], 0, 0, 0);

    #pragma unroll
    for (int mb = 0; mb < 4; ++mb) {
      int c = mb * 2 + (q >> 1);
      int sw = c ^ (l15 & 7);
      bf16x4 o = {(bf16)acc[mb][0], (bf16)acc[mb][1],
                  (bf16)acc[mb][2], (bf16)acc[mb][3]};
      *(bf16x4*)((char*)wstg + l15 * 128 + sw * 16 + (q & 1) * 8) = o;
    }
    asm volatile("s_waitcnt lgkmcnt(0)" ::: "memory");   // wave-scope fence
    uint4 v0 = *(const uint4*)((char*)wstg + wnode * 128 +
                               ((wch ^ (wnode & 7)) << 4));
    uint4 v1 = *(const uint4*)((char*)wstg + wnode * 128 +
                               (((wch + 1) ^ (wnode & 7)) << 4));
    bf16* op = Xout + (size_t)(nodeB + wnode) * 128 + dh * 64 + wch * 8;
    *(uint4*)(op) = v0;
    *(uint4*)(op + 8) = v1;
  }
}

// ---------------- aggregate (r5-proven structure): one segment/HALF-wave ---

__global__ __launch_bounds__(256) void aggf4_k(
    const bf16* __restrict__ Xab,
    const int* __restrict__ offsP, const int* __restrict__ bsums,
    const int* __restrict__ ids,
    bf16* __restrict__ HaggB, int gbase) {
  const int wv = threadIdx.x >> 6, lane = threadIdx.x & 63;
  const int h = lane >> 5, m = lane & 31;
  const int node = blockIdx.x * 8 + wv * 2 + h;
  const int slot = blockIdx.y, g = gbase + slot;
  const int ep = g & 1;
  const bf16* __restrict__ Xa = Xab + (size_t)slot * 12800000;
  const bf16* __restrict__ Xb = Xa + 6400000;
  const bf16* __restrict__ own = ep ? Xb : Xa;   // target side
  const bf16* __restrict__ oth = ep ? Xa : Xb;   // gathered side
  const int seg = g * V_NODES + node;
  const int beg = offsP[seg] + bsums[seg >> 9];
  const int end = offsP[seg + 1] + bsums[(seg + 1) >> 9];

  uint2 uo = *(const uint2*)(own + (size_t)node * 128 + m * 4);
  const float o0 = bflo(uo.x), o1 = bfhi(uo.x);
  const float o2 = bflo(uo.y), o3 = bfhi(uo.y);

  float s0 = 0.f, s1 = 0.f, s2 = 0.f, s3 = 0.f;
  int i = beg;
  for (; i + 2 <= end; i += 2) {
    int n0 = ids[i];
    int n1 = ids[i + 1];
    uint2 u0 = *(const uint2*)(oth + (size_t)n0 * 128 + m * 4);
    uint2 u1 = *(const uint2*)(oth + (size_t)n1 * 128 + m * 4);
    s0 += fmaxf(o0 + bflo(u0.x), 0.f) + fmaxf(o0 + bflo(u1.x), 0.f);
    s1 += fmaxf(o1 + bfhi(u0.x), 0.f) + fmaxf(o1 + bfhi(u1.x), 0.f);
    s2 += fmaxf(o2 + bflo(u0.y), 0.f) + fmaxf(o2 + bflo(u1.y), 0.f);
    s3 += fmaxf(o3 + bfhi(u0.y), 0.f) + fmaxf(o3 + bfhi(u1.y), 0.f);
  }
  if (i < end) {
    int n = ids[i];
    uint2 u = *(const uint2*)(oth + (size_t)n * 128 + m * 4);
    s0 += fmaxf(o0 + bflo(u.x), 0.f);
    s1 += fmaxf(o1 + bfhi(u.x), 0.f);
    s2 += fmaxf(o2 + bflo(u.y), 0.f);
    s3 += fmaxf(o3 + bfhi(u.y), 0.f);
  }
  bf16x4 st = {(bf16)s0, (bf16)s1, (bf16)s2, (bf16)s3};
  *(bf16x4*)(HaggB + ((size_t)g * V_NODES + node) * 128 + m * 4) = st;
}

// ---------------- dense GEMM2 (LDS-staged A; r12-proven ~55us) -------------

__global__ __launch_bounds__(256) void gemm2p_k(const bf16* __restrict__ HaggB,
                                                const bf16* __restrict__ w2t,
                                                float* __restrict__ out) {
  __shared__ __attribute__((aligned(16))) bf16 a_lds[32 * 128];   // 8KB

  const int tid = threadIdx.x, wv = tid >> 6, lane = tid & 63;
  const int l15 = lane & 15, q = lane >> 4;
  const int v0 = blockIdx.x * 32;

  const int srow = tid >> 3, sc0 = (tid & 7) * 2;
  bf16* sp0 = &a_lds[srow * 128 + ((sc0 ^ (srow & 7)) << 3)];
  bf16* sp1 = &a_lds[srow * 128 + (((sc0 + 1) ^ (srow & 7)) << 3)];

  const uint4* Hg = (const uint4*)(HaggB + (size_t)v0 * 128);
  uint4 s0 = Hg[tid * 2], s1 = Hg[tid * 2 + 1];

  f32x4 acc[2][2] = {};     // [mt][t]
  for (int g = 0; g < 8; ++g) {
    __syncthreads();
    *(uint4*)sp0 = s0;
    *(uint4*)sp1 = s1;
    if (g < 7) {
      const uint4* Hn = (const uint4*)(HaggB + (size_t)(g + 1) * 6400000 +
                                       (size_t)v0 * 128);
      s0 = Hn[tid * 2];
      s1 = Hn[tid * 2 + 1];
    }
    __syncthreads();

    const bf16* __restrict__ Wb = w2t + (size_t)g * 16384;
    #pragma unroll
    for (int kb = 0; kb < 4; ++kb) {
      bf16x8 a[2];
      #pragma unroll
      for (int mt = 0; mt < 2; ++mt) {
        int r = mt * 16 + l15;
        a[mt] = *(const bf16x8*)(&a_lds[r * 128 + (((kb * 4 + q) ^ (r & 7)) << 3)]);
      }
      #pragma unroll
      for (int t = 0; t < 2; ++t) {
        int n = (wv * 2 + t) * 16 + l15;
        bf16x8 b = *(const bf16x8*)(Wb + (size_t)n * 128 + kb * 32 + q * 8);
        #pragma unroll
        for (int mt = 0; mt < 2; ++mt)
          acc[mt][t] = __builtin_amdgcn_mfma_f32_16x16x32_bf16(a[mt], b, acc[mt][t], 0, 0, 0);
      }
    }
  }

  #pragma unroll
  for (int mt = 0; mt < 2; ++mt)
    #pragma unroll
    for (int r = 0; r < 4; ++r) {
      int row = v0 + mt * 16 + q * 4 + r;
      if (row < V_NODES) {
        #pragma unroll
        for (int t = 0; t < 2; ++t) {
          int col = (wv * 2 + t) * 16 + l15;
          out[(size_t)row * 128 + col] = fmaxf(acc[mt][t][r], 0.f);
        }
      }
    }
}

// ---------------- fallback edge kernel (round-0, proven 637us) -------------

__global__ __launch_bounds__(256) void edge_k(
    const bf16* __restrict__ embB,
    const int* __restrict__ a0, const int* __restrict__ a1,
    const int* __restrict__ a2, const int* __restrict__ a3,
    const bf16* __restrict__ w1t, const bf16* __restrict__ w2t,
    float* __restrict__ out) {

  __shared__ __attribute__((aligned(16))) bf16 w1_lds[128 * 256];
  __shared__ __attribute__((aligned(16))) bf16 h_lds[64 * 128];

  const int tid = threadIdx.x;
  const int g  = blockIdx.x >> 6;
  const int bs = blockIdx.x & 63;
  const int l = g >> 1, ep = g & 1;
  const int* __restrict__ adj = (l == 0) ? a0 : (l == 1) ? a1 : (l == 2) ? a2 : a3;

  {
    const uint4* w1g = (const uint4*)(w1t + (size_t)g * 128 * 256);
    #pragma unroll
    for (int i = 0; i < 16; ++i) {
      int j = i * 256 + tid;
      int n = j >> 5, c = j & 31;
      *(uint4*)(&w1_lds[n * 256 + ((c ^ (n & 7)) << 3)]) = w1g[j];
    }
  }
  __syncthreads();

  const int w    = tid >> 6;
  const int lane = tid & 63;
  const int wr = w >> 1, wc = w & 1;
  const int l15 = lane & 15, q = lane >> 4;
  const bf16* __restrict__ w2g = w2t + (size_t)g * 128 * 128;

  for (int t = bs; t < 2500; t += 64) {
    const int ebase = t * 64;
    int2 pr0 = ((const int2*)adj)[ebase + 32 * wr + l15];
    int2 pr1 = ((const int2*)adj)[ebase + 32 * wr + 16 + l15];
    pr0.x = clampV(pr0.x); pr0.y = clampV(pr0.y);
    pr1.x = clampV(pr1.x); pr1.y = clampV(pr1.y);

    f32x4 acc[2][4] = {};
    #pragma unroll
    for (int kb = 0; kb < 8; ++kb) {
      const int k = kb * 32 + q * 8;
      const int klo = k & 127;
      const int n0 = (kb < 4) ? pr0.x : pr0.y;
      const int n1 = (kb < 4) ? pr1.x : pr1.y;
      bf16x8 a[2], b[4];
      a[0] = *(const bf16x8*)(embB + (size_t)n0 * 128 + klo);
      a[1] = *(const bf16x8*)(embB + (size_t)n1 * 128 + klo);
      const int csw = ((kb << 2) + q);
      #pragma unroll
      for (int nt = 0; nt < 4; ++nt) {
        int n = 64 * wc + 16 * nt + l15;
        b[nt] = *(const bf16x8*)(&w1_lds[n * 256 + ((csw ^ (l15 & 7)) << 3)]);
      }
      #pragma unroll
      for (int mt = 0; mt < 2; ++mt)
        #pragma unroll
        for (int nt = 0; nt < 4; ++nt)
          acc[mt][nt] = __builtin_amdgcn_mfma_f32_16x16x32_bf16(a[mt], b[nt], acc[mt][nt], 0, 0, 0);
    }

    __syncthreads();
    #pragma unroll
    for (int mt = 0; mt < 2; ++mt)
      #pragma unroll
      for (int nt = 0; nt < 4; ++nt)
        #pragma unroll
        for (int r = 0; r < 4; ++r) {
          float v = acc[mt][nt][r];
          v = v > 0.f ? v : 0.f;
          int row = 32 * wr + 16 * mt + 4 * q + r;
          int col = 64 * wc + 16 * nt + l15;
          int c = col >> 3;
          h_lds[row * 128 + (((c ^ (row & 7)) << 3) | (col & 7))] = (bf16)v;
        }
    __syncthreads();

    f32x4 acc2[2][4] = {};
    #pragma unroll
    for (int kb = 0; kb < 4; ++kb) {
      const int k = kb * 32 + q * 8;
      const int csw = (kb << 2) + q;
      bf16x8 a[2], b[4];
      #pragma unroll
      for (int mt = 0; mt < 2; ++mt) {
        int row = 32 * wr + 16 * mt + l15;
        a[mt] = *(const bf16x8*)(&h_lds[row * 128 + ((csw ^ (row & 7)) << 3)]);
      }
      #pragma unroll
      for (int nt = 0; nt < 4; ++nt) {
        int n = 64 * wc + 16 * nt + l15;
        b[nt] = *(const bf16x8*)(w2g + n * 128 + k);
      }
      #pragma unroll
      for (int mt = 0; mt < 2; ++mt)
        #pragma unroll
        for (int nt = 0; nt < 4; ++nt)
          acc2[mt][nt] = __builtin_amdgcn_mfma_f32_16x16x32_bf16(a[mt], b[nt], acc2[mt][nt], 0, 0, 0);
    }

    #pragma unroll
    for (int mt = 0; mt < 2; ++mt)
      #pragma unroll
      for (int r = 0; r < 4; ++r) {
        int row = 32 * wr + 16 * mt + 4 * q + r;
        int2 pr = ((const int2*)adj)[ebase + row];
        int node = clampV(ep ? pr.y : pr.x);
        float* basep = out + (size_t)node * 128 + 64 * wc + l15;
        #pragma unroll
        for (int nt = 0; nt < 4; ++nt)
          unsafeAtomicAdd(basep + 16 * nt, acc2[mt][nt][r]);
      }
  }
}

// ---------------- host launch ----------------------------------------------

extern "C" void kernel_launch(void* const* d_in, const int* in_sizes, int n_in,
                              void* d_out, int out_size, void* d_ws, size_t ws_size,
                              hipStream_t stream) {
  const float* emb = (const float*)d_in[0];
  const int* a0 = (const int*)d_in[1];
  const int* a1 = (const int*)d_in[2];
  const int* a2 = (const int*)d_in[3];
  const int* a3 = (const int*)d_in[4];
  const float* W1 = (const float*)d_in[5];
  const float* W2 = (const float*)d_in[6];
  float* out = (float*)d_out;

  char* ws = (char*)d_ws;
  bf16* embB   = (bf16*)(ws);                    // 12,800,000
  bf16* w1t    = (bf16*)(ws + 12800000);         //    524,288
  bf16* w2t    = (bf16*)(ws + 13324288);         //    262,144
  int*  offsP  = (int*) (ws + 13586432);         //  1,600,016 (400001 ints + pad)
  int*  ids    = (int*) (ws + 15186448);         //  5,120,000 (other-endpoint only)
  int*  bsums  = (int*) (ws + 20306448);         //      3,136
  int*  counts = (int*) (ws + 20309584);         //  1,600,000
  bf16* HaggB  = (bf16*)(ws + 21909584);         // 102,400,000 (all 8 g)
  bf16* Xab    = (bf16*)(ws + 124309584);        // 102,400,000 (4 slots x Xa|Xb)
  const size_t need = 226709584;                 // == proven GG=4 bound (r6)
  // rankbuf (5.12MB) aliases the head of HaggB: written in fused_prep, read
  // in scatter2 — both strictly before aggf4's first write to HaggB.
  int* rankbuf = (int*)HaggB;

  if (ws_size >= need) {
    hipMemsetAsync(counts, 0, 1600000, stream);
    fused_prep_k<<<10286, 256, 0, stream>>>(emb, W1, W2, a0, a1, a2, a3,
                                            embB, w1t, w2t, counts, rankbuf);
    scan_a_k<<<NBLK_SCAN, 256, 0, stream>>>(counts, offsP, bsums);
    scan_b_k<<<1, 256, 0, stream>>>(bsums, offsP);

    scatter2_k<<<5000, 256, 0, stream>>>(a0, a1, a2, a3, offsP, bsums,
                                         rankbuf, ids);

    xab_k<<<2500, 256, 0, stream>>>(embB, w1t, Xab, 0);
    aggf4_k<<<dim3(6250, 4), 256, 0, stream>>>(Xab, offsP, bsums, ids, HaggB, 0);

    xab_k<<<2500, 256, 0, stream>>>(embB, w1t, Xab, 4);
    aggf4_k<<<dim3(6250, 4), 256, 0, stream>>>(Xab, offsP, bsums, ids, HaggB, 4);

    gemm2p_k<<<1563, 256, 0, stream>>>(HaggB, w2t, out);
  } else {
    prep_emb_k<<<6250, 256, 0, stream>>>(emb, embB);
    prep_w1_k<<<1024, 256, 0, stream>>>(W1, w1t);
    prep_w2_k<<<512, 256, 0, stream>>>(W2, w2t);
    hipMemsetAsync(d_out, 0, 25600000, stream);
    edge_k<<<512, 256, 0, stream>>>(embB, a0, a1, a2, a3, w1t, w2t, out);
    relu_k<<<6250, 256, 0, stream>>>(out);
  }
}